// Round 3
// baseline (2162.308 us; speedup 1.0000x reference)
//
#include <hip/hip_runtime.h>

#define LQN 900
#define BN 16
#define DN 256
#define NHN 8
#define HDN 32
#define LVN 13294
#define NTOK (LQN*BN)   // 14400

typedef unsigned short u16;
typedef unsigned int u32;

__device__ __forceinline__ float sf(float v){
  return (v==v && v > -1e30f && v < 1e30f) ? v : 0.f;
}
__device__ __forceinline__ float bf2f(u16 u){
  union { u32 i; float f; } x; x.i = ((u32)u) << 16; return x.f;
}
__device__ __forceinline__ float bf2fs(u16 u){ return sf(bf2f(u)); }
__device__ __forceinline__ u16 f2bf(float f){
  union { float f; u32 i; } x; x.f = f;
  u32 u = x.i;
  u32 r = (u + 0x7fffu + ((u >> 16) & 1u)) >> 16;
  return (u16)r;
}

// ---------------- sentinel (diagnostic) ----------------
__global__ __launch_bounds__(256) void sentinel_kernel(float code, float* __restrict__ out, int n){
  int i = blockIdx.x*256 + threadIdx.x;
  if (i < n) out[i] = code;
}

// ---------------- elementwise add (fp32) ----------------
__global__ __launch_bounds__(256) void add_kernel(const float* __restrict__ a,
                                                  const float* __restrict__ b,
                                                  float* __restrict__ out){
  size_t i = (size_t)blockIdx.x*256 + threadIdx.x;
  out[i] = sf(a[i]) + sf(b[i]);
}

// ---------------- GEMM: out[n,o] = A[n,:] . W[o,:] + bias[o] ----------------
// A, W, bias fp32. MODE 0: fp32 out. MODE 1: fp32 + ReLU. MODE 2: bf16 out in
// (B,NH,LV,HD) "val" layout (row r = lv*16+b).
template<int MODE>
__global__ __launch_bounds__(256) void gemm_kernel(const float* __restrict__ A,
    const float* __restrict__ W, const float* __restrict__ bias,
    void* __restrict__ outp, int M, int K, int OD)
{
  __shared__ float AsT[32][132];   // [k][m]
  __shared__ float WsT[32][132];   // [k][n]
  const int t = threadIdx.x;
  const int mq = t & 15, nq = t >> 4;
  const int rowBase = blockIdx.x * 128;
  const int colBase = blockIdx.y * 128;
  float acc[8][8];
  #pragma unroll
  for (int i=0;i<8;i++)
    #pragma unroll
    for (int j=0;j<8;j++) acc[i][j]=0.f;

  for (int kk=0; kk<K; kk+=32){
    #pragma unroll
    for (int i=0;i<4;i++){
      int f = t + i*256;
      int row = f >> 3, k4 = (f & 7) << 2;
      int gr = rowBase + row; if (gr >= M) gr = M-1;
      float4 av = *(const float4*)(A + (size_t)gr*K + kk + k4);
      AsT[k4+0][row]=sf(av.x); AsT[k4+1][row]=sf(av.y);
      AsT[k4+2][row]=sf(av.z); AsT[k4+3][row]=sf(av.w);
    }
    #pragma unroll
    for (int i=0;i<4;i++){
      int f = t + i*256;
      int row = f >> 3, k4 = (f & 7) << 2;
      float4 wv4 = *(const float4*)(W + (size_t)(colBase+row)*K + kk + k4);
      WsT[k4+0][row]=sf(wv4.x); WsT[k4+1][row]=sf(wv4.y);
      WsT[k4+2][row]=sf(wv4.z); WsT[k4+3][row]=sf(wv4.w);
    }
    __syncthreads();
    #pragma unroll 8
    for (int k=0;k<32;k++){
      float4 a0 = *(const float4*)&AsT[k][mq*4];
      float4 a1 = *(const float4*)&AsT[k][64+mq*4];
      float4 b0 = *(const float4*)&WsT[k][nq*4];
      float4 b1 = *(const float4*)&WsT[k][64+nq*4];
      float av8[8] = {a0.x,a0.y,a0.z,a0.w,a1.x,a1.y,a1.z,a1.w};
      float bv8[8] = {b0.x,b0.y,b0.z,b0.w,b1.x,b1.y,b1.z,b1.w};
      #pragma unroll
      for (int i2=0;i2<8;i2++)
        #pragma unroll
        for (int j2=0;j2<8;j2++) acc[i2][j2] += av8[i2]*bv8[j2];
    }
    __syncthreads();
  }
  float bv[8];
  #pragma unroll
  for (int j=0;j<8;j++){
    int c = colBase + ((j<4)? (nq*4+j) : (60+nq*4+j));
    bv[j] = sf(bias[c]);
  }
  #pragma unroll
  for (int i=0;i<8;i++){
    int lr = (i<4)? (mq*4+i) : (60+mq*4+i);
    int r = rowBase + lr;
    if (r >= M) continue;
    float v[8];
    #pragma unroll
    for (int j=0;j<8;j++){
      v[j] = acc[i][j] + bv[j];
      if (MODE==1) v[j] = fmaxf(v[j], 0.f);
    }
    if (MODE==2){
      u16* vout = (u16*)outp;
      int b = r & 15, lv = r >> 4;
      #pragma unroll
      for (int g=0; g<2; g++){
        int c0 = colBase + (g? (64+nq*4) : (nq*4));
        int h = c0 >> 5, hd = c0 & 31;
        size_t idx = (((size_t)(b*8+h)*LVN + lv) << 5) + hd;
        ushort4 sv;
        sv.x = f2bf(v[g*4+0]); sv.y=f2bf(v[g*4+1]); sv.z=f2bf(v[g*4+2]); sv.w=f2bf(v[g*4+3]);
        *(ushort4*)(vout + idx) = sv;
      }
    } else {
      float* fo = (float*)outp;
      float4 s0 = make_float4(v[0],v[1],v[2],v[3]);
      float4 s1 = make_float4(v[4],v[5],v[6],v[7]);
      *(float4*)(fo + (size_t)r*OD + colBase + nq*4) = s0;
      *(float4*)(fo + (size_t)r*OD + colBase + 64 + nq*4) = s1;
    }
  }
}

// ---------------- flash-style self attention ----------------
__global__ __launch_bounds__(256) void attn_kernel(const float* __restrict__ q,
    const float* __restrict__ k, const float* __restrict__ v, float* __restrict__ o)
{
  const int bh = blockIdx.y; const int b = bh >> 3, h = bh & 7;
  const int qt = blockIdx.x * 64;
  const int t = threadIdx.x;
  __shared__ float qsT[32][64];
  __shared__ float ksT[32][64];
  __shared__ float vs[64][32];
  __shared__ float ST[64][64];
  __shared__ float marr[64], larr[64], alpharr[64];
  __shared__ float red[4][64];

  const float scale = 0.17677669529663687f;
  #pragma unroll
  for (int i=0;i<2;i++){
    int f = t + i*256; int row = f>>3; int k4 = (f&7)<<2;
    int l = qt + row; if (l >= LQN) l = LQN-1;
    float4 qv = *(const float4*)(q + ((size_t)(l*BN + b))*DN + h*HDN + k4);
    qsT[k4+0][row]=sf(qv.x)*scale; qsT[k4+1][row]=sf(qv.y)*scale;
    qsT[k4+2][row]=sf(qv.z)*scale; qsT[k4+3][row]=sf(qv.w)*scale;
  }
  if (t < 64){ marr[t] = -30000.f; larr[t] = 0.f; }
  float acc[4][2] = {{0.f,0.f},{0.f,0.f},{0.f,0.f},{0.f,0.f}};
  const int rq = t & 15, cq = t >> 4;
  const int r = t & 63, part = t >> 6;

  for (int kt=0; kt<15; kt++){
    int kbase = kt*64;
    float4 kr[2], vr[2];
    #pragma unroll
    for (int i=0;i<2;i++){
      int f = t + i*256; int row = f>>3; int k4 = (f&7)<<2;
      int kl = kbase + row; if (kl >= LQN) kl = LQN-1;
      size_t base = ((size_t)(kl*BN+b))*DN + h*HDN + k4;
      kr[i] = *(const float4*)(k + base);
      vr[i] = *(const float4*)(v + base);
    }
    __syncthreads();   // prev iter PV done
    #pragma unroll
    for (int i=0;i<2;i++){
      int f = t + i*256; int row = f>>3; int k4 = (f&7)<<2;
      ksT[k4+0][row]=sf(kr[i].x); ksT[k4+1][row]=sf(kr[i].y);
      ksT[k4+2][row]=sf(kr[i].z); ksT[k4+3][row]=sf(kr[i].w);
      vs[row][k4+0]=sf(vr[i].x); vs[row][k4+1]=sf(vr[i].y);
      vs[row][k4+2]=sf(vr[i].z); vs[row][k4+3]=sf(vr[i].w);
    }
    __syncthreads();
    float s[4][4];
    #pragma unroll
    for (int i=0;i<4;i++){ s[i][0]=0.f; s[i][1]=0.f; s[i][2]=0.f; s[i][3]=0.f; }
    #pragma unroll 8
    for (int kd=0; kd<32; kd++){
      float4 aq = *(const float4*)&qsT[kd][rq*4];
      float4 bk = *(const float4*)&ksT[kd][cq*4];
      s[0][0]+=aq.x*bk.x; s[0][1]+=aq.x*bk.y; s[0][2]+=aq.x*bk.z; s[0][3]+=aq.x*bk.w;
      s[1][0]+=aq.y*bk.x; s[1][1]+=aq.y*bk.y; s[1][2]+=aq.y*bk.z; s[1][3]+=aq.y*bk.w;
      s[2][0]+=aq.z*bk.x; s[2][1]+=aq.z*bk.y; s[2][2]+=aq.z*bk.z; s[2][3]+=aq.z*bk.w;
      s[3][0]+=aq.w*bk.x; s[3][1]+=aq.w*bk.y; s[3][2]+=aq.w*bk.z; s[3][3]+=aq.w*bk.w;
    }
    #pragma unroll
    for (int j=0;j<4;j++){
      int kg = kbase + cq*4 + j;
      float4 col = (kg < LQN) ? make_float4(s[0][j],s[1][j],s[2][j],s[3][j])
                              : make_float4(-30000.f,-30000.f,-30000.f,-30000.f);
      *(float4*)&ST[cq*4+j][rq*4] = col;
    }
    __syncthreads();
    float mx = -30000.f;
    #pragma unroll
    for (int j=part*16; j<part*16+16; j++) mx = fmaxf(mx, ST[j][r]);
    red[part][r] = mx;
    __syncthreads();
    if (t < 64){
      float m_old = marr[t];
      float mnew = fmaxf(fmaxf(red[0][t],red[1][t]), fmaxf(red[2][t],red[3][t]));
      mnew = fmaxf(m_old, mnew);
      alpharr[t] = __expf(m_old - mnew);
      marr[t] = mnew;
    }
    __syncthreads();
    float mnew = marr[r];
    float psum = 0.f;
    #pragma unroll
    for (int j=part*16; j<part*16+16; j++){
      float p = __expf(ST[j][r] - mnew);
      ST[j][r] = p; psum += p;
    }
    red[part][r] = psum;
    __syncthreads();
    if (t < 64) larr[t] = larr[t]*alpharr[t] + red[0][t]+red[1][t]+red[2][t]+red[3][t];
    #pragma unroll
    for (int i=0;i<4;i++){ float al = alpharr[rq*4+i]; acc[i][0]*=al; acc[i][1]*=al; }
    #pragma unroll 8
    for (int j=0;j<64;j++){
      float4 p4 = *(const float4*)&ST[j][rq*4];
      float2 v2 = *(const float2*)&vs[j][cq*2];
      acc[0][0]+=p4.x*v2.x; acc[0][1]+=p4.x*v2.y;
      acc[1][0]+=p4.y*v2.x; acc[1][1]+=p4.y*v2.y;
      acc[2][0]+=p4.z*v2.x; acc[2][1]+=p4.z*v2.y;
      acc[3][0]+=p4.w*v2.x; acc[3][1]+=p4.w*v2.y;
    }
  }
  __syncthreads();
  #pragma unroll
  for (int i=0;i<4;i++){
    int l = qt + rq*4 + i;
    if (l < LQN){
      float inv = 1.0f / fmaxf(larr[rq*4+i], 1e-20f);
      size_t base = ((size_t)(l*BN+b))*DN + h*HDN + cq*2;
      o[base+0] = acc[i][0]*inv;
      o[base+1] = acc[i][1]*inv;
    }
  }
}

// ---------------- fused residual + LayerNorm (all fp32) ----------------
__global__ __launch_bounds__(256) void ln_kernel(const float* __restrict__ a,
    const float* __restrict__ bsrc, const float* __restrict__ g, const float* __restrict__ beta,
    float* __restrict__ outp, int trans)
{
  int n = blockIdx.x, t = threadIdx.x;
  __shared__ float red[4];
  size_t bidx;
  if (trans){ int bb = n & 15; int l = n >> 4; bidx = ((size_t)(bb*LQN + l))*DN + t; }
  else bidx = (size_t)n*DN + t;
  float v = sf(a[(size_t)n*DN + t]) + sf(bsrc[bidx]);
  float s = v;
  #pragma unroll
  for (int o2=32;o2>0;o2>>=1) s += __shfl_xor(s, o2);
  if ((t & 63)==0) red[t>>6] = s;
  __syncthreads();
  float mean = (red[0]+red[1]+red[2]+red[3]) * (1.0f/256.0f);
  float d = v - mean;
  __syncthreads();
  float sq = d*d;
  #pragma unroll
  for (int o2=32;o2>0;o2>>=1) sq += __shfl_xor(sq, o2);
  if ((t & 63)==0) red[t>>6] = sq;
  __syncthreads();
  float var = (red[0]+red[1]+red[2]+red[3]) * (1.0f/256.0f);
  float rs = rsqrtf(var + 1e-5f);
  outp[(size_t)n*DN + t] = d*rs*sf(g[t]) + sf(beta[t]);
}

// ---------------- MS deformable sampling ----------------
// val bf16 (B,NH,LV,HD); off fp32 (N,256); aw logits fp32 (N,128); refp fp32 (LQ,B,4,2)
__global__ __launch_bounds__(256) void sampler_kernel(const u16* __restrict__ val,
    const float* __restrict__ off, const float* __restrict__ aw,
    const float* __restrict__ refp, float* __restrict__ out)
{
  int gid = blockIdx.x*256 + threadIdx.x;
  int hd = gid & 31;
  int unit = gid >> 5;
  int b = unit / 7200;
  int rem = unit - b*7200;
  int l = rem >> 3;
  int h = rem & 7;
  int n = l*BN + b;
  float wv[16]; float mx = -1e30f;
  #pragma unroll
  for (int i=0;i<16;i++){ wv[i] = sf(aw[(size_t)n*128 + h*16 + i]); mx = fmaxf(mx, wv[i]); }
  float ssum = 0.f;
  #pragma unroll
  for (int i=0;i<16;i++){ wv[i] = __expf(wv[i]-mx); ssum += wv[i]; }
  float winv = 1.0f/fmaxf(ssum, 1e-20f);
  const u16* vb = val + ((size_t)(b*8+h))*LVN*HDN;
  const int WSs[4] = {100,50,25,13};
  const int ST0[4] = {0,10000,12500,13125};
  float acc = 0.f;
  #pragma unroll
  for (int lvl=0;lvl<4;lvl++){
    int w = WSs[lvl]; int hh = w; int st = ST0[lvl];
    float rx = sf(refp[((size_t)n*4 + lvl)*2 + 0]);
    float ry = sf(refp[((size_t)n*4 + lvl)*2 + 1]);
    float invw = 1.0f/(float)w;
    #pragma unroll
    for (int p=0;p<4;p++){
      float ox = sf(off[(size_t)n*DN + (size_t)((h*4+lvl)*4+p)*2 + 0]);
      float oy = sf(off[(size_t)n*DN + (size_t)((h*4+lvl)*4+p)*2 + 1]);
      float x = (rx + ox*invw)*(float)w - 0.5f;
      float y = (ry + oy*invw)*(float)hh - 0.5f;
      float x0f = floorf(x), y0f = floorf(y);
      float wx = x - x0f, wy = y - y0f;
      int x0 = (int)x0f, y0 = (int)y0f;
      float aww = wv[lvl*4+p]*winv;
      int x1 = x0+1, y1 = y0+1;
      int x0c = min(max(x0,0),w-1), x1c = min(max(x1,0),w-1);
      int y0c = min(max(y0,0),hh-1), y1c = min(max(y1,0),hh-1);
      bool vx0 = (x0>=0)&&(x0<w), vx1 = (x1>=0)&&(x1<w);
      bool vy0 = (y0>=0)&&(y0<hh), vy1 = (y1>=0)&&(y1<hh);
      float v00 = (vx0&&vy0) ? bf2fs(vb[(size_t)(st + y0c*w + x0c)*HDN + hd]) : 0.f;
      float v01 = (vx1&&vy0) ? bf2fs(vb[(size_t)(st + y0c*w + x1c)*HDN + hd]) : 0.f;
      float v10 = (vx0&&vy1) ? bf2fs(vb[(size_t)(st + y1c*w + x0c)*HDN + hd]) : 0.f;
      float v11 = (vx1&&vy1) ? bf2fs(vb[(size_t)(st + y1c*w + x1c)*HDN + hd]) : 0.f;
      acc += aww*( v00*(1.f-wx)*(1.f-wy) + v01*wx*(1.f-wy) + v10*(1.f-wx)*wy + v11*wx*wy );
    }
  }
  out[((size_t)b*LQN + l)*DN + h*HDN + hd] = acc;
}

// ---------------- launch ----------------
extern "C" void kernel_launch(void* const* d_in, const int* in_sizes, int n_in,
                              void* d_out, int out_size, void* d_ws, size_t ws_size,
                              hipStream_t stream) {
  // ---- diagnostics: encode environment mismatches into the output ----
  static const int EXP_SIZES[28] = {
    3686400,3686400,115200,54452224,196608,768,65536,256,65536,256,
    32768,128,65536,256,65536,256,262144,1024,262144,256,
    256,256,256,256,256,256,8,4};
  const size_t WS_NEEDED = 108904448ull + 5ull*14745600ull;  // 182,632,448
  float code = 0.f;
  if (n_in != 28) code = 2100.f;
  else {
    for (int i=0;i<28;i++) if (in_sizes[i] != EXP_SIZES[i]) { code = 2000.f + 32.f*i; break; }
  }
  if (code == 0.f && out_size != 3686400) code = 3000.f;
  if (code == 0.f && ws_size < WS_NEEDED) code = 1000.f + (float)(ws_size >> 20);
  if (code != 0.f){
    sentinel_kernel<<<(out_size+255)/256,256,0,stream>>>(code, (float*)d_out, out_size);
    return;
  }

  const float* tgt   = (const float*)d_in[0];
  const float* pos   = (const float*)d_in[1];
  const float* refp  = (const float*)d_in[2];
  const float* mem   = (const float*)d_in[3];
  const float* in_w  = (const float*)d_in[4];
  const float* in_b  = (const float*)d_in[5];
  const float* out_w = (const float*)d_in[6];
  const float* out_b = (const float*)d_in[7];
  const float* so_w  = (const float*)d_in[8];
  const float* so_b  = (const float*)d_in[9];
  const float* aw_w  = (const float*)d_in[10];
  const float* aw_b  = (const float*)d_in[11];
  const float* vp_w  = (const float*)d_in[12];
  const float* vp_b  = (const float*)d_in[13];
  const float* mo_w  = (const float*)d_in[14];
  const float* mo_b  = (const float*)d_in[15];
  const float* l1_w  = (const float*)d_in[16];
  const float* l1_b  = (const float*)d_in[17];
  const float* l2_w  = (const float*)d_in[18];
  const float* l2_b  = (const float*)d_in[19];
  const float* n1g   = (const float*)d_in[20];
  const float* n1b   = (const float*)d_in[21];
  const float* n2g   = (const float*)d_in[22];
  const float* n2b   = (const float*)d_in[23];
  const float* n3g   = (const float*)d_in[24];
  const float* n3b   = (const float*)d_in[25];

  char* ws = (char*)d_ws;
  u16*   VAL = (u16*)ws;                       // 108,904,448 B (bf16 val)
  float* HID = (float*)ws;                     // reuses VAL region (fp32 ffn hidden, 59 MB)
  float* X  = (float*)(ws + 108904448);
  float* Q  = X  + 3686400;
  float* Kb = Q  + 3686400;
  float* Vb = Kb + 3686400;
  float* O  = Vb + 3686400;

  const int NT = NTOK;         // 14400
  const int MV = LVN*BN;       // 212704

  // 1. x = tgt + pos
  add_kernel<<<NT,256,0,stream>>>(tgt, pos, X);
  // 2. q,k,v projections
  gemm_kernel<0><<<dim3(113,2),256,0,stream>>>(X,   in_w,          in_b,     (void*)Q,  NT, 256, 256);
  gemm_kernel<0><<<dim3(113,2),256,0,stream>>>(X,   in_w+65536,    in_b+256, (void*)Kb, NT, 256, 256);
  gemm_kernel<0><<<dim3(113,2),256,0,stream>>>(tgt, in_w+131072,   in_b+512, (void*)Vb, NT, 256, 256);
  // 3. self attention
  attn_kernel<<<dim3(15,128),256,0,stream>>>(Q, Kb, Vb, O);
  // 4. out proj -> sa (X)
  gemm_kernel<0><<<dim3(113,2),256,0,stream>>>(O, out_w, out_b, (void*)X, NT, 256, 256);
  // 5. tgt2 = LN(tgt + sa) -> Q
  ln_kernel<<<NT,256,0,stream>>>(tgt, X, n2g, n2b, Q, 0);
  // 6. q2 = tgt2 + pos -> Kb
  add_kernel<<<NT,256,0,stream>>>(Q, pos, Kb);
  // 7. val projection (bf16, (B,NH,LV,HD))
  gemm_kernel<2><<<dim3(1662,2),256,0,stream>>>(mem, vp_w, vp_b, (void*)VAL, MV, 256, 256);
  // 8. sampling offsets (Vb) + attn weight logits (O)
  gemm_kernel<0><<<dim3(113,2),256,0,stream>>>(Kb, so_w, so_b, (void*)Vb, NT, 256, 256);
  gemm_kernel<0><<<dim3(113,1),256,0,stream>>>(Kb, aw_w, aw_b, (void*)O,  NT, 256, 128);
  // 9. deformable sampling -> X ((B,LQ,D))
  sampler_kernel<<<NT,256,0,stream>>>(VAL, Vb, O, refp, X);
  // 10. ms out proj -> Kb (ca, (B,LQ,D))
  gemm_kernel<0><<<dim3(113,2),256,0,stream>>>(X, mo_w, mo_b, (void*)Kb, NT, 256, 256);
  // 11. tgt3 = LN(tgt2 + ca^T) -> Vb
  ln_kernel<<<NT,256,0,stream>>>(Q, Kb, n1g, n1b, Vb, 1);
  // 12. ffn1 + relu -> HID
  gemm_kernel<1><<<dim3(113,8),256,0,stream>>>(Vb, l1_w, l1_b, (void*)HID, NT, 256, 1024);
  // 13. ffn2 -> X
  gemm_kernel<0><<<dim3(113,2),256,0,stream>>>(HID, l2_w, l2_b, (void*)X, NT, 1024, 256);
  // 14. out = LN(tgt3 + t2) -> d_out (fp32)
  ln_kernel<<<NT,256,0,stream>>>(Vb, X, n3g, n3b, (float*)d_out, 0);
}

// Round 4
// 1134.747 us; speedup vs baseline: 1.9055x; 1.9055x over previous
//
#include <hip/hip_runtime.h>

#define LQN 900
#define BN 16
#define DN 256
#define NHN 8
#define HDN 32
#define LVN 13294
#define NTOK (LQN*BN)   // 14400

typedef unsigned short u16;
typedef unsigned int u32;
typedef __attribute__((ext_vector_type(8))) short bf16x8;
typedef __attribute__((ext_vector_type(4))) float f32x4;

__device__ __forceinline__ float sf(float v){
  return (v==v && v > -1e30f && v < 1e30f) ? v : 0.f;
}
__device__ __forceinline__ float bf2f(u16 u){
  union { u32 i; float f; } x; x.i = ((u32)u) << 16; return x.f;
}
__device__ __forceinline__ u16 f2bf(float f){
  union { float f; u32 i; } x; x.f = f;
  u32 u = x.i;
  u32 r = (u + 0x7fffu + ((u >> 16) & 1u)) >> 16;
  return (u16)r;
}

// ---------------- sentinel (diagnostic) ----------------
__global__ __launch_bounds__(256) void sentinel_kernel(float code, float* __restrict__ out, int n){
  int i = blockIdx.x*256 + threadIdx.x;
  if (i < n) out[i] = code;
}

// ---------------- elementwise add (fp32) ----------------
__global__ __launch_bounds__(256) void add_kernel(const float* __restrict__ a,
                                                  const float* __restrict__ b,
                                                  float* __restrict__ out){
  size_t i = (size_t)blockIdx.x*256 + threadIdx.x;
  out[i] = a[i] + b[i];
}

// ---------------- MFMA GEMM: out[r,c] = A[r,:] . W[c,:] + bias[c] ----------------
// A fp32 [M][K]; W fp32 [OD][K]; converted to bf16 in LDS (frag-order layout).
// 128x128 block tile, 4 waves in 2x2, each wave 4x4 MFMA tiles of 16x16x32.
// MODE 0: fp32 out [M][OD]. MODE 1: +ReLU. MODE 2: bf16 out in (B,NH,LV,HD)
// "val" layout (row r = lv*16+b, col c -> h=c>>5, hd=c&31).
template<int MODE>
__global__ __launch_bounds__(256) void gemm_mfma(const float* __restrict__ A,
    const float* __restrict__ W, const float* __restrict__ bias,
    void* __restrict__ outp, int M, int K, int OD)
{
  // frag-order: buf[sub*512 + (k>>3)*128 + idx*8 + (k&7)], sub = row/16, idx = row%16
  __shared__ u16 Abuf[4096];   // 128 rows x 32 k, bf16 (8 KB)
  __shared__ u16 Bbuf[4096];
  const int t = threadIdx.x;
  const int rowBase = blockIdx.x*128, colBase = blockIdx.y*128;
  const int wid = t>>6, lane = t&63;
  const int quad = lane>>4, lrow = lane&15;
  const int wm = (wid&1)*64, wn = (wid>>1)*64;
  f32x4 acc[4][4];
  #pragma unroll
  for (int i=0;i<4;i++)
    #pragma unroll
    for (int j=0;j<4;j++) acc[i][j] = (f32x4){0.f,0.f,0.f,0.f};

  for (int kk=0; kk<K; kk+=32){
    #pragma unroll
    for (int i=0;i<4;i++){
      int f = t + i*256;
      int row = f >> 3, k4 = (f & 7) << 2;
      int gr = rowBase + row; if (gr >= M) gr = M-1;
      float4 av = *(const float4*)(A + (size_t)gr*K + kk + k4);
      ushort4 sv; sv.x=f2bf(av.x); sv.y=f2bf(av.y); sv.z=f2bf(av.z); sv.w=f2bf(av.w);
      *(ushort4*)&Abuf[(row>>4)*512 + (k4>>3)*128 + (row&15)*8 + (k4&7)] = sv;
    }
    #pragma unroll
    for (int i=0;i<4;i++){
      int f = t + i*256;
      int row = f >> 3, k4 = (f & 7) << 2;
      float4 wv4 = *(const float4*)(W + (size_t)(colBase+row)*K + kk + k4);
      ushort4 sv; sv.x=f2bf(wv4.x); sv.y=f2bf(wv4.y); sv.z=f2bf(wv4.z); sv.w=f2bf(wv4.w);
      *(ushort4*)&Bbuf[(row>>4)*512 + (k4>>3)*128 + (row&15)*8 + (k4&7)] = sv;
    }
    __syncthreads();
    bf16x8 af[4];
    #pragma unroll
    for (int mt=0;mt<4;mt++)
      af[mt] = *(const bf16x8*)&Abuf[((wm>>4)+mt)*512 + quad*128 + lrow*8];
    #pragma unroll
    for (int nt=0;nt<4;nt++){
      bf16x8 bfr = *(const bf16x8*)&Bbuf[((wn>>4)+nt)*512 + quad*128 + lrow*8];
      #pragma unroll
      for (int mt=0;mt<4;mt++)
        acc[mt][nt] = __builtin_amdgcn_mfma_f32_16x16x32_bf16(af[mt], bfr, acc[mt][nt], 0, 0, 0);
    }
    __syncthreads();
  }
  // epilogue: D row = quad*4+reg (m), col = lrow (n)
  #pragma unroll
  for (int nt=0;nt<4;nt++){
    int c = colBase + wn + nt*16 + lrow;
    float bb = bias[c];
    #pragma unroll
    for (int mt=0;mt<4;mt++){
      #pragma unroll
      for (int rg=0;rg<4;rg++){
        int r = rowBase + wm + mt*16 + quad*4 + rg;
        if (r < M){
          float vv = acc[mt][nt][rg] + bb;
          if (MODE==1) vv = fmaxf(vv, 0.f);
          if (MODE==2){
            u16* vo = (u16*)outp;
            int b2 = r & 15, lv = r >> 4;
            int h2 = c >> 5, hd = c & 31;
            vo[(((size_t)(b2*8+h2)*LVN + lv) << 5) + hd] = f2bf(vv);
          } else {
            ((float*)outp)[(size_t)r*OD + c] = vv;
          }
        }
      }
    }
  }
}

// ---------------- flash-style self attention (unchanged, fp32) ----------------
__global__ __launch_bounds__(256) void attn_kernel(const float* __restrict__ q,
    const float* __restrict__ k, const float* __restrict__ v, float* __restrict__ o)
{
  const int bh = blockIdx.y; const int b = bh >> 3, h = bh & 7;
  const int qt = blockIdx.x * 64;
  const int t = threadIdx.x;
  __shared__ float qsT[32][64];
  __shared__ float ksT[32][64];
  __shared__ float vs[64][32];
  __shared__ float ST[64][64];
  __shared__ float marr[64], larr[64], alpharr[64];
  __shared__ float red[4][64];

  const float scale = 0.17677669529663687f;
  #pragma unroll
  for (int i=0;i<2;i++){
    int f = t + i*256; int row = f>>3; int k4 = (f&7)<<2;
    int l = qt + row; if (l >= LQN) l = LQN-1;
    float4 qv = *(const float4*)(q + ((size_t)(l*BN + b))*DN + h*HDN + k4);
    qsT[k4+0][row]=sf(qv.x)*scale; qsT[k4+1][row]=sf(qv.y)*scale;
    qsT[k4+2][row]=sf(qv.z)*scale; qsT[k4+3][row]=sf(qv.w)*scale;
  }
  if (t < 64){ marr[t] = -30000.f; larr[t] = 0.f; }
  float acc[4][2] = {{0.f,0.f},{0.f,0.f},{0.f,0.f},{0.f,0.f}};
  const int rq = t & 15, cq = t >> 4;
  const int r = t & 63, part = t >> 6;

  for (int kt=0; kt<15; kt++){
    int kbase = kt*64;
    float4 kr[2], vr[2];
    #pragma unroll
    for (int i=0;i<2;i++){
      int f = t + i*256; int row = f>>3; int k4 = (f&7)<<2;
      int kl = kbase + row; if (kl >= LQN) kl = LQN-1;
      size_t base = ((size_t)(kl*BN+b))*DN + h*HDN + k4;
      kr[i] = *(const float4*)(k + base);
      vr[i] = *(const float4*)(v + base);
    }
    __syncthreads();   // prev iter PV done
    #pragma unroll
    for (int i=0;i<2;i++){
      int f = t + i*256; int row = f>>3; int k4 = (f&7)<<2;
      ksT[k4+0][row]=sf(kr[i].x); ksT[k4+1][row]=sf(kr[i].y);
      ksT[k4+2][row]=sf(kr[i].z); ksT[k4+3][row]=sf(kr[i].w);
      vs[row][k4+0]=sf(vr[i].x); vs[row][k4+1]=sf(vr[i].y);
      vs[row][k4+2]=sf(vr[i].z); vs[row][k4+3]=sf(vr[i].w);
    }
    __syncthreads();
    float s[4][4];
    #pragma unroll
    for (int i=0;i<4;i++){ s[i][0]=0.f; s[i][1]=0.f; s[i][2]=0.f; s[i][3]=0.f; }
    #pragma unroll 8
    for (int kd=0; kd<32; kd++){
      float4 aq = *(const float4*)&qsT[kd][rq*4];
      float4 bk = *(const float4*)&ksT[kd][cq*4];
      s[0][0]+=aq.x*bk.x; s[0][1]+=aq.x*bk.y; s[0][2]+=aq.x*bk.z; s[0][3]+=aq.x*bk.w;
      s[1][0]+=aq.y*bk.x; s[1][1]+=aq.y*bk.y; s[1][2]+=aq.y*bk.z; s[1][3]+=aq.y*bk.w;
      s[2][0]+=aq.z*bk.x; s[2][1]+=aq.z*bk.y; s[2][2]+=aq.z*bk.z; s[2][3]+=aq.z*bk.w;
      s[3][0]+=aq.w*bk.x; s[3][1]+=aq.w*bk.y; s[3][2]+=aq.w*bk.z; s[3][3]+=aq.w*bk.w;
    }
    #pragma unroll
    for (int j=0;j<4;j++){
      int kg = kbase + cq*4 + j;
      float4 col = (kg < LQN) ? make_float4(s[0][j],s[1][j],s[2][j],s[3][j])
                              : make_float4(-30000.f,-30000.f,-30000.f,-30000.f);
      *(float4*)&ST[cq*4+j][rq*4] = col;
    }
    __syncthreads();
    float mx = -30000.f;
    #pragma unroll
    for (int j=part*16; j<part*16+16; j++) mx = fmaxf(mx, ST[j][r]);
    red[part][r] = mx;
    __syncthreads();
    if (t < 64){
      float m_old = marr[t];
      float mnew = fmaxf(fmaxf(red[0][t],red[1][t]), fmaxf(red[2][t],red[3][t]));
      mnew = fmaxf(m_old, mnew);
      alpharr[t] = __expf(m_old - mnew);
      marr[t] = mnew;
    }
    __syncthreads();
    float mnew = marr[r];
    float psum = 0.f;
    #pragma unroll
    for (int j=part*16; j<part*16+16; j++){
      float p = __expf(ST[j][r] - mnew);
      ST[j][r] = p; psum += p;
    }
    red[part][r] = psum;
    __syncthreads();
    if (t < 64) larr[t] = larr[t]*alpharr[t] + red[0][t]+red[1][t]+red[2][t]+red[3][t];
    #pragma unroll
    for (int i=0;i<4;i++){ float al = alpharr[rq*4+i]; acc[i][0]*=al; acc[i][1]*=al; }
    #pragma unroll 8
    for (int j=0;j<64;j++){
      float4 p4 = *(const float4*)&ST[j][rq*4];
      float2 v2 = *(const float2*)&vs[j][cq*2];
      acc[0][0]+=p4.x*v2.x; acc[0][1]+=p4.x*v2.y;
      acc[1][0]+=p4.y*v2.x; acc[1][1]+=p4.y*v2.y;
      acc[2][0]+=p4.z*v2.x; acc[2][1]+=p4.z*v2.y;
      acc[3][0]+=p4.w*v2.x; acc[3][1]+=p4.w*v2.y;
    }
  }
  __syncthreads();
  #pragma unroll
  for (int i=0;i<4;i++){
    int l = qt + rq*4 + i;
    if (l < LQN){
      float inv = 1.0f / fmaxf(larr[rq*4+i], 1e-20f);
      size_t base = ((size_t)(l*BN+b))*DN + h*HDN + cq*2;
      o[base+0] = acc[i][0]*inv;
      o[base+1] = acc[i][1]*inv;
    }
  }
}

// ---------------- fused residual + LayerNorm (fp32) ----------------
__global__ __launch_bounds__(256) void ln_kernel(const float* __restrict__ a,
    const float* __restrict__ bsrc, const float* __restrict__ g, const float* __restrict__ beta,
    float* __restrict__ outp, int trans)
{
  int n = blockIdx.x, t = threadIdx.x;
  __shared__ float red[4];
  size_t bidx;
  if (trans){ int bb = n & 15; int l = n >> 4; bidx = ((size_t)(bb*LQN + l))*DN + t; }
  else bidx = (size_t)n*DN + t;
  float v = a[(size_t)n*DN + t] + bsrc[bidx];
  float s = v;
  #pragma unroll
  for (int o2=32;o2>0;o2>>=1) s += __shfl_xor(s, o2);
  if ((t & 63)==0) red[t>>6] = s;
  __syncthreads();
  float mean = (red[0]+red[1]+red[2]+red[3]) * (1.0f/256.0f);
  float d = v - mean;
  __syncthreads();
  float sq = d*d;
  #pragma unroll
  for (int o2=32;o2>0;o2>>=1) sq += __shfl_xor(sq, o2);
  if ((t & 63)==0) red[t>>6] = sq;
  __syncthreads();
  float var = (red[0]+red[1]+red[2]+red[3]) * (1.0f/256.0f);
  float rs = rsqrtf(var + 1e-5f);
  outp[(size_t)n*DN + t] = d*rs*g[t] + beta[t];
}

// ---------------- MS deformable sampling (u32 loads, batched MLP) ----------------
// val bf16 (B,NH,LV,HD); 16 lanes per (b,l,h) unit, each lane covers an hd pair.
// Per level: precompute 16 clamped addrs + validity-folded weights, then issue
// 16 unconditional u32 loads back-to-back (max outstanding vmcnt).
__global__ __launch_bounds__(256) void sampler_kernel(const u16* __restrict__ val,
    const float* __restrict__ off, const float* __restrict__ aw,
    const float* __restrict__ refp, float* __restrict__ out)
{
  int gid = blockIdx.x*256 + threadIdx.x;
  int hd2 = gid & 15;
  int unit = gid >> 4;
  int b = unit / 7200;
  int rem = unit - b*7200;
  int l = rem >> 3;
  int h = rem & 7;
  int n = l*BN + b;
  const float* awp = aw + (size_t)n*128 + h*16;
  float wvv[16]; float mx = -1e30f;
  #pragma unroll
  for (int i=0;i<16;i++){ wvv[i] = awp[i]; mx = fmaxf(mx, wvv[i]); }
  float ssum = 0.f;
  #pragma unroll
  for (int i=0;i<16;i++){ wvv[i] = __expf(wvv[i]-mx); ssum += wvv[i]; }
  float winv = 1.0f/ssum;
  const u16* vb = val + (size_t)(b*8+h)*LVN*HDN + hd2*2;
  const float* offp = off + (size_t)n*DN + h*32;
  const float* rp = refp + (size_t)n*8;
  const int WSs[4] = {100,50,25,13};
  const int ST0[4] = {0,10000,12500,13125};
  float acc0 = 0.f, acc1 = 0.f;
  #pragma unroll
  for (int lvl=0;lvl<4;lvl++){
    const int w_ = WSs[lvl];
    const int st = ST0[lvl];
    const float fw = (float)w_;
    float rx = rp[lvl*2+0], ry = rp[lvl*2+1];
    int lin[16]; float cw[16];
    #pragma unroll
    for (int p=0;p<4;p++){
      float ox = offp[lvl*8 + p*2 + 0];
      float oy = offp[lvl*8 + p*2 + 1];
      float x = rx*fw + ox - 0.5f;
      float y = ry*fw + oy - 0.5f;
      float x0f = floorf(x), y0f = floorf(y);
      float wx = x - x0f, wy = y - y0f;
      int x0 = (int)x0f, y0 = (int)y0f;
      int x1 = x0+1, y1 = y0+1;
      int x0c = min(max(x0,0),w_-1), x1c = min(max(x1,0),w_-1);
      int y0c = min(max(y0,0),w_-1), y1c = min(max(y1,0),w_-1);
      float fx0 = (x0>=0 && x0<w_) ? 1.f : 0.f;
      float fx1 = (x1>=0 && x1<w_) ? 1.f : 0.f;
      float fy0 = (y0>=0 && y0<w_) ? 1.f : 0.f;
      float fy1 = (y1>=0 && y1<w_) ? 1.f : 0.f;
      float aww = wvv[lvl*4+p]*winv;
      lin[p*4+0] = st + y0c*w_ + x0c;  cw[p*4+0] = aww*(1.f-wx)*(1.f-wy)*fx0*fy0;
      lin[p*4+1] = st + y0c*w_ + x1c;  cw[p*4+1] = aww*wx*(1.f-wy)*fx1*fy0;
      lin[p*4+2] = st + y1c*w_ + x0c;  cw[p*4+2] = aww*(1.f-wx)*wy*fx0*fy1;
      lin[p*4+3] = st + y1c*w_ + x1c;  cw[p*4+3] = aww*wx*wy*fx1*fy1;
    }
    u32 dat[16];
    #pragma unroll
    for (int s2=0;s2<16;s2++) dat[s2] = *(const u32*)(vb + (size_t)lin[s2]*HDN);
    #pragma unroll
    for (int s2=0;s2<16;s2++){
      acc0 += cw[s2]*bf2f((u16)(dat[s2]&0xffffu));
      acc1 += cw[s2]*bf2f((u16)(dat[s2]>>16));
    }
  }
  *(float2*)(out + ((size_t)b*LQN + l)*DN + h*HDN + hd2*2) = make_float2(acc0, acc1);
}

// ---------------- launch ----------------
extern "C" void kernel_launch(void* const* d_in, const int* in_sizes, int n_in,
                              void* d_out, int out_size, void* d_ws, size_t ws_size,
                              hipStream_t stream) {
  static const int EXP_SIZES[28] = {
    3686400,3686400,115200,54452224,196608,768,65536,256,65536,256,
    32768,128,65536,256,65536,256,262144,1024,262144,256,
    256,256,256,256,256,256,8,4};
  const size_t WS_NEEDED = 108904448ull + 5ull*14745600ull;  // 182,632,448
  float code = 0.f;
  if (n_in != 28) code = 2100.f;
  else {
    for (int i=0;i<28;i++) if (in_sizes[i] != EXP_SIZES[i]) { code = 2000.f + 32.f*i; break; }
  }
  if (code == 0.f && out_size != 3686400) code = 3000.f;
  if (code == 0.f && ws_size < WS_NEEDED) code = 1000.f + (float)(ws_size >> 20);
  if (code != 0.f){
    sentinel_kernel<<<(out_size+255)/256,256,0,stream>>>(code, (float*)d_out, out_size);
    return;
  }

  const float* tgt   = (const float*)d_in[0];
  const float* pos   = (const float*)d_in[1];
  const float* refp  = (const float*)d_in[2];
  const float* mem   = (const float*)d_in[3];
  const float* in_w  = (const float*)d_in[4];
  const float* in_b  = (const float*)d_in[5];
  const float* out_w = (const float*)d_in[6];
  const float* out_b = (const float*)d_in[7];
  const float* so_w  = (const float*)d_in[8];
  const float* so_b  = (const float*)d_in[9];
  const float* aw_w  = (const float*)d_in[10];
  const float* aw_b  = (const float*)d_in[11];
  const float* vp_w  = (const float*)d_in[12];
  const float* vp_b  = (const float*)d_in[13];
  const float* mo_w  = (const float*)d_in[14];
  const float* mo_b  = (const float*)d_in[15];
  const float* l1_w  = (const float*)d_in[16];
  const float* l1_b  = (const float*)d_in[17];
  const float* l2_w  = (const float*)d_in[18];
  const float* l2_b  = (const float*)d_in[19];
  const float* n1g   = (const float*)d_in[20];
  const float* n1b   = (const float*)d_in[21];
  const float* n2g   = (const float*)d_in[22];
  const float* n2b   = (const float*)d_in[23];
  const float* n3g   = (const float*)d_in[24];
  const float* n3b   = (const float*)d_in[25];

  char* ws = (char*)d_ws;
  u16*   VAL = (u16*)ws;                       // 108,904,448 B (bf16 val)
  float* HID = (float*)ws;                     // reuses VAL region (fp32 ffn hidden, 59 MB)
  float* X  = (float*)(ws + 108904448);
  float* Q  = X  + 3686400;
  float* Kb = Q  + 3686400;
  float* Vb = Kb + 3686400;
  float* O  = Vb + 3686400;

  const int NT = NTOK;         // 14400
  const int MV = LVN*BN;       // 212704

  // 1. x = tgt + pos
  add_kernel<<<NT,256,0,stream>>>(tgt, pos, X);
  // 2. q,k,v projections (MFMA)
  gemm_mfma<0><<<dim3(113,2),256,0,stream>>>(X,   in_w,          in_b,     (void*)Q,  NT, 256, 256);
  gemm_mfma<0><<<dim3(113,2),256,0,stream>>>(X,   in_w+65536,    in_b+256, (void*)Kb, NT, 256, 256);
  gemm_mfma<0><<<dim3(113,2),256,0,stream>>>(tgt, in_w+131072,   in_b+512, (void*)Vb, NT, 256, 256);
  // 3. self attention
  attn_kernel<<<dim3(15,128),256,0,stream>>>(Q, Kb, Vb, O);
  // 4. out proj -> sa (X)
  gemm_mfma<0><<<dim3(113,2),256,0,stream>>>(O, out_w, out_b, (void*)X, NT, 256, 256);
  // 5. tgt2 = LN(tgt + sa) -> Q
  ln_kernel<<<NT,256,0,stream>>>(tgt, X, n2g, n2b, Q, 0);
  // 6. q2 = tgt2 + pos -> Kb
  add_kernel<<<NT,256,0,stream>>>(Q, pos, Kb);
  // 7. val projection (bf16, (B,NH,LV,HD))
  gemm_mfma<2><<<dim3(1662,2),256,0,stream>>>(mem, vp_w, vp_b, (void*)VAL, MV, 256, 256);
  // 8. sampling offsets (Vb) + attn weight logits (O)
  gemm_mfma<0><<<dim3(113,2),256,0,stream>>>(Kb, so_w, so_b, (void*)Vb, NT, 256, 256);
  gemm_mfma<0><<<dim3(113,1),256,0,stream>>>(Kb, aw_w, aw_b, (void*)O,  NT, 256, 128);
  // 9. deformable sampling -> X ((B,LQ,D))
  sampler_kernel<<<7200,256,0,stream>>>(VAL, Vb, O, refp, X);
  // 10. ms out proj -> Kb (ca, (B,LQ,D))
  gemm_mfma<0><<<dim3(113,2),256,0,stream>>>(X, mo_w, mo_b, (void*)Kb, NT, 256, 256);
  // 11. tgt3 = LN(tgt2 + ca^T) -> Vb
  ln_kernel<<<NT,256,0,stream>>>(Q, Kb, n1g, n1b, Vb, 1);
  // 12. ffn1 + relu -> HID
  gemm_mfma<1><<<dim3(113,8),256,0,stream>>>(Vb, l1_w, l1_b, (void*)HID, NT, 256, 1024);
  // 13. ffn2 -> X
  gemm_mfma<0><<<dim3(113,2),256,0,stream>>>(HID, l2_w, l2_b, (void*)X, NT, 1024, 256);
  // 14. out = LN(tgt3 + t2) -> d_out (fp32)
  ln_kernel<<<NT,256,0,stream>>>(Vb, X, n3g, n3b, (float*)d_out, 0);
}